// Round 5
// baseline (406.567 us; speedup 1.0000x reference)
//
#include <hip/hip_runtime.h>
#include <hip/hip_bf16.h>
#include <stdint.h>

// Problem constants (fixed by reference): N=8192, F=1024, F_=64, H=4
#define NN 8192
#define FF 1024
#define FD 64
#define NH 4
#define CC 256    // H*F_
#define MAXE 192  // max neighbors per row (mean ~34, max over 8192 rows ~60; 23 sigma)

typedef __attribute__((ext_vector_type(8))) short short8;
typedef __attribute__((ext_vector_type(4))) float f32x4;

__device__ __forceinline__ short bf16_rne(float f) {
    union { float f; uint32_t u; } v; v.f = f;
    uint32_t r = (v.u + 0x7FFFu + ((v.u >> 16) & 1u)) >> 16;
    return (short)(r & 0xFFFFu);
}
__device__ __forceinline__ float bf2f(short s) {
    union { uint32_t u; float f; } v; v.u = ((uint32_t)(uint16_t)s) << 16;
    return v.f;
}

// ---------------------------------------------------------------------------
// Kernel 0a: W (H,F,F_) fp32 -> Wt[h][n][k] bf16 (transposed, contiguous k).
// Tiny (1 MB read); must run before mega (gemm blocks read Wt).
__global__ __launch_bounds__(256) void wt_kernel(const float* __restrict__ W,
                                                 short* __restrict__ Wt) {
    int gid = blockIdx.x * 256 + threadIdx.x;
    int k = gid & 1023;
    int n = (gid >> 10) & 63;
    int h = gid >> 16;
    Wt[gid] = bf16_rne(W[(h << 16) + k * 64 + n]);
}

// ---------------------------------------------------------------------------
// Mega-kernel: blocks [0,512) = GEMM tiles, blocks [512, 8704) = A-row scan.
// Rationale: scan is pure HBM streaming (VALU/MFMA idle), gemm is
// compute/LDS-bound (HBM mostly idle after L2 warm) -> co-residency overlaps
// them; total ~= max, not sum. Branch is block-uniform (no divergence).
//
// GEMM: feats = X*W per head, bf16 MFMA, fp32 acc, BM=64/BN=64/BK=32.
//   X is converted fp32->bf16 in-register during staging (xb_kernel gone).
//   Epilogue: bf16 feats + packed per-node score vectors
//   s_self4[row] / s_neigh4[row] (float4, component = head).
// SCAN: stream A row, compact nonzero columns into nbr/cnt (CSR, fixed 192).
__global__ __launch_bounds__(256) void mega_kernel(const float* __restrict__ X,
                                                   const short* __restrict__ Wt,
                                                   const float* __restrict__ attn_a,
                                                   const float* __restrict__ A,
                                                   short* __restrict__ featb,
                                                   float* __restrict__ s_self4,
                                                   float* __restrict__ s_neigh4,
                                                   int* __restrict__ nbr,
                                                   int* __restrict__ cnt) {
    __shared__ short Xs[64 * 40];
    __shared__ short Ws[64 * 40];
    const int b = blockIdx.x;
    const int t = threadIdx.x;

    if (b < 512) {
        // ---------------- GEMM branch ----------------
        const int h  = b & 3;
        const int m0 = (b >> 2) * 64;
        const int wave = t >> 6, lane = t & 63;
        const int q = lane >> 4, nl = lane & 15;
        const int srow = t >> 2, sk8 = (t & 3) * 8;

        f32x4 acc0 = {0.f,0.f,0.f,0.f}, acc1 = {0.f,0.f,0.f,0.f};
        f32x4 acc2 = {0.f,0.f,0.f,0.f}, acc3 = {0.f,0.f,0.f,0.f};

        const float* Xp = X + (size_t)(m0 + srow) * FF + sk8;
        const short* Wp = Wt + (size_t)(h * 64 + srow) * FF + sk8;

        for (int k0 = 0; k0 < FF; k0 += 32) {
            float4 x0 = *(const float4*)(Xp + k0);
            float4 x1 = *(const float4*)(Xp + k0 + 4);
            short8 wv = *(const short8*)(Wp + k0);
            short8 xv;
            xv[0] = bf16_rne(x0.x); xv[1] = bf16_rne(x0.y);
            xv[2] = bf16_rne(x0.z); xv[3] = bf16_rne(x0.w);
            xv[4] = bf16_rne(x1.x); xv[5] = bf16_rne(x1.y);
            xv[6] = bf16_rne(x1.z); xv[7] = bf16_rne(x1.w);
            *(short8*)(&Xs[srow * 40 + sk8]) = xv;
            *(short8*)(&Ws[srow * 40 + sk8]) = wv;
            __syncthreads();
            short8 a  = *(const short8*)(&Xs[(wave * 16 + nl) * 40 + q * 8]);
            short8 b0 = *(const short8*)(&Ws[( 0 + nl) * 40 + q * 8]);
            short8 b1 = *(const short8*)(&Ws[(16 + nl) * 40 + q * 8]);
            short8 b2 = *(const short8*)(&Ws[(32 + nl) * 40 + q * 8]);
            short8 b3 = *(const short8*)(&Ws[(48 + nl) * 40 + q * 8]);
            acc0 = __builtin_amdgcn_mfma_f32_16x16x32_bf16(a, b0, acc0, 0, 0, 0);
            acc1 = __builtin_amdgcn_mfma_f32_16x16x32_bf16(a, b1, acc1, 0, 0, 0);
            acc2 = __builtin_amdgcn_mfma_f32_16x16x32_bf16(a, b2, acc2, 0, 0, 0);
            acc3 = __builtin_amdgcn_mfma_f32_16x16x32_bf16(a, b3, acc3, 0, 0, 0);
            __syncthreads();
        }
        // C/D layout: col = nl (+16 per acc), row = m0 + wave*16 + q*4 + r
        const int row = m0 + wave * 16 + q * 4;
        const int colbase = h * 64 + nl;
        for (int r = 0; r < 4; ++r) {
            short* fr = featb + (size_t)(row + r) * CC + colbase;
            fr[ 0] = bf16_rne(acc0[r]);
            fr[16] = bf16_rne(acc1[r]);
            fr[32] = bf16_rne(acc2[r]);
            fr[48] = bf16_rne(acc3[r]);
        }
        // Fused s_self/s_neigh (fp32 accs, full precision), packed by node.
        const float A0 = attn_a[h * 128 + nl],      A1 = attn_a[h * 128 + nl + 16];
        const float A2 = attn_a[h * 128 + nl + 32], A3 = attn_a[h * 128 + nl + 48];
        const float B0 = attn_a[h * 128 + 64 + nl],      B1 = attn_a[h * 128 + 64 + nl + 16];
        const float B2 = attn_a[h * 128 + 64 + nl + 32], B3 = attn_a[h * 128 + 64 + nl + 48];
        for (int r = 0; r < 4; ++r) {
            float ps = acc0[r] * A0 + acc1[r] * A1 + acc2[r] * A2 + acc3[r] * A3;
            float pn = acc0[r] * B0 + acc1[r] * B1 + acc2[r] * B2 + acc3[r] * B3;
            for (int off = 1; off < 16; off <<= 1) {
                ps += __shfl_xor(ps, off);
                pn += __shfl_xor(pn, off);
            }
            if (nl == 0) {
                s_self4 [(row + r) * 4 + h] = ps;
                s_neigh4[(row + r) * 4 + h] = pn;
            }
        }
    } else {
        // ---------------- SCAN branch ----------------
        int* idx = (int*)Xs;        // reuse LDS
        int* c   = (int*)Ws;
        const int row = b - 512;
        if (t == 0) *c = 0;
        __syncthreads();
        const f32x4* A4 = (const f32x4*)(A + (size_t)row * NN);
        for (int r = 0; r < 8; ++r) {
            int c4 = r * 256 + t;
            f32x4 v = __builtin_nontemporal_load(&A4[c4]);
            if (v.x > 0.5f) { int p = atomicAdd(c, 1); if (p < MAXE) idx[p] = c4 * 4 + 0; }
            if (v.y > 0.5f) { int p = atomicAdd(c, 1); if (p < MAXE) idx[p] = c4 * 4 + 1; }
            if (v.z > 0.5f) { int p = atomicAdd(c, 1); if (p < MAXE) idx[p] = c4 * 4 + 2; }
            if (v.w > 0.5f) { int p = atomicAdd(c, 1); if (p < MAXE) idx[p] = c4 * 4 + 3; }
        }
        __syncthreads();
        int n = min(*c, MAXE);
        if (t < n) nbr[row * MAXE + t] = idx[t];
        if (t == 0) cnt[row] = n;
    }
}

// ---------------------------------------------------------------------------
// Kernel 2: per-row softmax + weighted gather. Block = row, wave = head.
// Scores: cooperative, ONE float4 load per neighbor serves all 4 heads,
// transposed via LDS. PV: 8 neighbors/iter x 8 lanes x short8 (16 B) loads.
__global__ __launch_bounds__(256) void smax_kernel(const int* __restrict__ nbr,
                                                   const int* __restrict__ cnt,
                                                   const short* __restrict__ featb,
                                                   const float* __restrict__ s_self4,
                                                   const float* __restrict__ s_neigh4,
                                                   const float* __restrict__ bias,
                                                   float* __restrict__ out) {
    __shared__ int js[MAXE];
    __shared__ float scs[NH][MAXE];
    const int row = blockIdx.x;
    const int t = threadIdx.x;
    const int h = t >> 6, lane = t & 63;
    const int n = cnt[row];
    if (t < n) js[t] = nbr[row * MAXE + t];
    __syncthreads();

    // cooperative leaky-relu scores, all heads per neighbor (n <= 192 < 256)
    const f32x4 ss = *(const f32x4*)(s_self4 + row * 4);
    if (t < n) {
        f32x4 sn = *(const f32x4*)(s_neigh4 + js[t] * 4);
        #pragma unroll
        for (int hh = 0; hh < NH; ++hh) {
            float s = ss[hh] + sn[hh];
            scs[hh][t] = s > 0.f ? s : 0.2f * s;
        }
    }
    __syncthreads();

    // per-wave (head) softmax over scs[h][0..n)
    float m = -1e30f;
    #pragma unroll
    for (int i = 0; i < 3; ++i) {
        int e = lane + 64 * i;
        if (e < n) m = fmaxf(m, scs[h][e]);
    }
    for (int off = 1; off < 64; off <<= 1) m = fmaxf(m, __shfl_xor(m, off));
    float dsum = 0.f;
    #pragma unroll
    for (int i = 0; i < 3; ++i) {
        int e = lane + 64 * i;
        if (e < n) {
            float p = __expf(scs[h][e] - m);
            scs[h][e] = p;       // in-place: wave h owns row h (no barrier)
            dsum += p;
        }
    }
    for (int off = 1; off < 64; off <<= 1) dsum += __shfl_xor(dsum, off);

    // PV gather: sub-slot = neighbor, 8 lanes own 8 bf16 cols each (16 B)
    const int sub = lane >> 3;   // 0..7
    const int l8  = lane & 7;    // owns cols l8*8 .. +7
    const short* fb = featb + h * 64 + l8 * 8;
    f32x4 accA = {0.f,0.f,0.f,0.f}, accB = {0.f,0.f,0.f,0.f};
    for (int e = sub; e < n; e += 8) {
        int j = js[e];
        float p = scs[h][e];
        short8 f = *(const short8*)(fb + (size_t)j * CC);
        accA[0] = fmaf(p, bf2f(f[0]), accA[0]);
        accA[1] = fmaf(p, bf2f(f[1]), accA[1]);
        accA[2] = fmaf(p, bf2f(f[2]), accA[2]);
        accA[3] = fmaf(p, bf2f(f[3]), accA[3]);
        accB[0] = fmaf(p, bf2f(f[4]), accB[0]);
        accB[1] = fmaf(p, bf2f(f[5]), accB[1]);
        accB[2] = fmaf(p, bf2f(f[6]), accB[2]);
        accB[3] = fmaf(p, bf2f(f[7]), accB[3]);
    }
    #pragma unroll
    for (int k = 0; k < 4; ++k) {
        accA[k] += __shfl_xor(accA[k], 8);
        accA[k] += __shfl_xor(accA[k], 16);
        accA[k] += __shfl_xor(accA[k], 32);
        accB[k] += __shfl_xor(accB[k], 8);
        accB[k] += __shfl_xor(accB[k], 16);
        accB[k] += __shfl_xor(accB[k], 32);
    }
    if (sub == 0) {
        float rd = 1.0f / dsum;
        const float* bp = bias + h * 64 + l8 * 8;
        f32x4 oA, oB;
        #pragma unroll
        for (int k = 0; k < 4; ++k) {
            oA[k] = fmaxf(accA[k] * rd + bp[k],     0.f);
            oB[k] = fmaxf(accB[k] * rd + bp[k + 4], 0.f);
        }
        float* op = out + (size_t)row * CC + h * 64 + l8 * 8;
        *(f32x4*)op       = oA;
        *(f32x4*)(op + 4) = oB;
    }
}

// ---------------------------------------------------------------------------
extern "C" void kernel_launch(void* const* d_in, const int* in_sizes, int n_in,
                              void* d_out, int out_size, void* d_ws, size_t ws_size,
                              hipStream_t stream) {
    const float* X      = (const float*)d_in[0];   // (8192, 1024)
    const float* A      = (const float*)d_in[1];   // (8192, 8192)
    const float* W      = (const float*)d_in[2];   // (4, 1024, 64)
    const float* attn_a = (const float*)d_in[3];   // (4, 128, 1)
    const float* bias   = (const float*)d_in[4];   // (4, 64)
    float* out = (float*)d_out;                    // (8192, 256)

    char* ws = (char*)d_ws;
    short* featb    = (short*)ws;                         //  4194304 B (bf16 feats)
    float* s_self4  = (float*)(ws + 4194304);             //   131072 B (N x 4, packed)
    float* s_neigh4 = (float*)(ws + 4325376);             //   131072 B
    short* Wt       = (short*)(ws + 4456448);             //   524288 B
    int*   nbr      = (int*)  (ws + 4980736);             //  6291456 B (8192*192*4)
    int*   cnt      = (int*)  (ws + 11272192);            //    32768 B

    wt_kernel  <<<1024, 256, 0, stream>>>(W, Wt);
    mega_kernel<<<512 + NN, 256, 0, stream>>>(X, Wt, attn_a, A,
                                              featb, s_self4, s_neigh4, nbr, cnt);
    smax_kernel<<<NN, 256, 0, stream>>>(nbr, cnt, featb, s_self4, s_neigh4, bias, out);
}